// Round 3
// baseline (121.156 us; speedup 1.0000x reference)
//
#include <hip/hip_runtime.h>
#include <hip/hip_bf16.h>

#define B_SZ 16384
#define E_SZ 128
#define H_SZ 256
#define A_SZ 20
#define K_SZ 384           // H + E
#define BH   (B_SZ * H_SZ) // 4194304

typedef __attribute__((ext_vector_type(8))) short  short8v;
typedef __attribute__((ext_vector_type(4))) float  f32x4;
typedef __attribute__((ext_vector_type(2))) float  f32x2;
typedef __attribute__((ext_vector_type(4))) unsigned short ushort4v;
typedef __attribute__((ext_vector_type(2))) unsigned short ushort2v;

__device__ __forceinline__ unsigned short f2bf(float f) {
    union { float f; unsigned u; } v; v.f = f;
    unsigned r = v.u + 0x7fffu + ((v.u >> 16) & 1u);   // RNE
    return (unsigned short)(r >> 16);
}

__device__ __forceinline__ float wsum(float v) {
    #pragma unroll
    for (int off = 32; off > 0; off >>= 1) v += __shfl_xor(v, off, 64);
    return v;
}

__device__ __forceinline__ float sigm(float x) { return 1.0f / (1.0f + __expf(-x)); }

struct Ptr8 { const float* p[8]; };

// ---------------- Kernel 1: weight transpose+pack: Wt[g][n][k] bf16 ----------
__global__ __launch_bounds__(256) void pack_w(Ptr8 ws, unsigned short* __restrict__ Wt)
{
    const int g = blockIdx.z, nt = blockIdx.y, kt = blockIdx.x;
    __shared__ float tile[64][65];
    const float* W = ws.p[g];
    const int c = threadIdx.x & 63, r0 = threadIdx.x >> 6;
    #pragma unroll
    for (int i = 0; i < 16; ++i) {
        int r = r0 + 4 * i;
        tile[r][c] = W[(size_t)(kt * 64 + r) * H_SZ + nt * 64 + c];
    }
    __syncthreads();
    #pragma unroll
    for (int i = 0; i < 16; ++i) {
        int rr = r0 + 4 * i;
        Wt[(size_t)g * 256 * 384 + (size_t)(nt * 64 + rr) * K_SZ + kt * 64 + c] =
            f2bf(tile[c][rr]);
    }
}

// ---------------- Kernel 2: fully fused attn + 8-gate GEMM + LSTM epilogue ---
// 256 blocks (1/CU) x 512 threads. Block owns 64 rows.
// LDS map: A1 tile [64 rows][768B, 16B-slot XOR-swz] @0      (49152 B)
//          A2 tile                                   @49152  (49152 B)
//          gl  exchange 8g x 16r x 64 f32, XOR-swz   @98304  (32768 B)  = 128 KiB
__global__ __launch_bounds__(512, 2) void fused(
    const float* __restrict__ x1, const float* __restrict__ x2,
    const float* __restrict__ h,  const float* __restrict__ c1,
    const float* __restrict__ c2, const float* __restrict__ wa,
    const unsigned short* __restrict__ Wt, Ptr8 bias, float* __restrict__ out)
{
    __shared__ char smem[131072];
    const int tid = threadIdx.x, w = tid >> 6, lane = tid & 63;
    const int row0 = blockIdx.x * 64;

    // ================= Phase A: attention + pack rows into LDS ==============
    {
        const f32x4 wah  = *(const f32x4*)(wa + 4 * lane);
        const f32x2 wax1 = *(const f32x2*)(wa + H_SZ + 2 * lane);
        const f32x2 wax2 = *(const f32x2*)(wa + H_SZ + E_SZ + 2 * lane);

        f32x4 hA, hB; f32x2 x1A, x1B; f32x2 xA[A_SZ], xB[A_SZ];

        auto issue = [&](f32x4& hv, f32x2& x1v, f32x2 (&xv)[A_SZ], int lr) {
            const int row = row0 + w * 8 + lr;
            hv  = *(const f32x4*)(h  + (size_t)row * H_SZ + 4 * lane);
            x1v = *(const f32x2*)(x1 + (size_t)row * E_SZ + 2 * lane);
            const float* x2r = x2 + (size_t)row * A_SZ * E_SZ + 2 * lane;
            #pragma unroll
            for (int a = 0; a < A_SZ; ++a) xv[a] = *(const f32x2*)(x2r + a * E_SZ);
        };
        auto process = [&](const f32x4& hv, const f32x2& x1v, f32x2 (&xv)[A_SZ], int lr) {
            float base = hv.x * wah.x + hv.y * wah.y + hv.z * wah.z + hv.w * wah.w
                       + x1v.x * wax1.x + x1v.y * wax1.y;
            float sp[A_SZ];
            #pragma unroll
            for (int a = 0; a < A_SZ; ++a) sp[a] = xv[a].x * wax2.x + xv[a].y * wax2.y;
            base = wsum(base);
            #pragma unroll
            for (int a = 0; a < A_SZ; ++a) sp[a] = wsum(sp[a]) + base;
            float mx = sp[0];
            #pragma unroll
            for (int a = 1; a < A_SZ; ++a) mx = fmaxf(mx, sp[a]);
            float s = 0.0f;
            #pragma unroll
            for (int a = 0; a < A_SZ; ++a) { sp[a] = __expf(sp[a] - mx); s += sp[a]; }
            const float inv = 1.0f / s;
            float m0 = 0.0f, m1 = 0.0f;
            #pragma unroll
            for (int a = 0; a < A_SZ; ++a) { m0 += sp[a] * xv[a].x; m1 += sp[a] * xv[a].y; }
            m0 *= inv; m1 *= inv;

            const int rl = w * 8 + lr;
            // h part: 8B at slot (lane>>1), swizzled by row
            ushort4v hb;
            hb.x = f2bf(hv.x); hb.y = f2bf(hv.y); hb.z = f2bf(hv.z); hb.w = f2bf(hv.w);
            const int offH = rl * 768 + (((lane >> 1) ^ (rl & 7)) << 4) + (lane & 1) * 8;
            *(ushort4v*)(smem + offH)         = hb;
            *(ushort4v*)(smem + 49152 + offH) = hb;
            // x part: 4B at slot 32+(lane>>2)
            const int offX = rl * 768 + ((32 + ((lane >> 2) ^ (rl & 7))) << 4) + (lane & 3) * 4;
            ushort2v x1b; x1b.x = f2bf(x1v.x); x1b.y = f2bf(x1v.y);
            *(ushort2v*)(smem + offX) = x1b;
            ushort2v mb; mb.x = f2bf(m0); mb.y = f2bf(m1);
            *(ushort2v*)(smem + 49152 + offX) = mb;
        };

        issue(hA, x1A, xA, 0);
        #pragma unroll
        for (int lr = 0; lr < 8; ++lr) {
            if (lr & 1) { if (lr < 7) issue(hA, x1A, xA, lr + 1); process(hB, x1B, xB, lr); }
            else        { if (lr < 7) issue(hB, x1B, xB, lr + 1); process(hA, x1A, xA, lr); }
        }
    }
    __syncthreads();

    // ================= Phase B: GEMM + epilogue, per 64-col block ===========
    const int fr = lane & 15;
    const int hi = lane >> 4;
    const unsigned short* Wg = Wt + (size_t)w * 256 * 384;
    const char* tb = smem + (w >> 2) * 49152;     // this wave's cell tile

    const int erow = tid >> 5;            // 0..15 epilogue row
    const int ecol = (tid & 31) * 2;      // 0..62 epilogue col (f32x2)
    float* glf = (float*)(smem + 98304);
    const int eswz = (erow & 7) << 2;

    for (int nc = 0; nc < 4; ++nc) {
        const int col0 = nc * 64;

        f32x4 acc[4][4];
        #pragma unroll
        for (int mi = 0; mi < 4; ++mi)
            #pragma unroll
            for (int ni = 0; ni < 4; ++ni) acc[mi][ni] = (f32x4){0.f, 0.f, 0.f, 0.f};

        const unsigned short* bbase = Wg + (size_t)(col0 + fr) * K_SZ + hi * 8;

        #pragma unroll
        for (int kk = 0; kk < 12; ++kk) {
            short8v bfr[4], afr[4];
            #pragma unroll
            for (int ni = 0; ni < 4; ++ni)
                bfr[ni] = *(const short8v*)(bbase + (size_t)ni * 16 * K_SZ + kk * 32);
            #pragma unroll
            for (int mi = 0; mi < 4; ++mi) {
                const int R = mi * 16 + fr;
                const int byteoff = R * 768 + ((((kk << 2) + hi) ^ (R & 7)) << 4);
                afr[mi] = *(const short8v*)(tb + byteoff);
            }
            #pragma unroll
            for (int mi = 0; mi < 4; ++mi)
                #pragma unroll
                for (int ni = 0; ni < 4; ++ni)
                    acc[mi][ni] = __builtin_amdgcn_mfma_f32_16x16x32_bf16(
                        afr[mi], bfr[ni], acc[mi][ni], 0, 0, 0);
        }

        // prefetch c1/c2 + biases for this col block (hides HBM/L2 latency
        // under the exchange barriers below)
        const int col = col0 + ecol;
        f32x2 c1p[4], c2p[4];
        #pragma unroll
        for (int sp = 0; sp < 4; ++sp) {
            const int b = row0 + sp * 16 + erow;
            c1p[sp] = *(const f32x2*)(c1 + (size_t)b * H_SZ + col);
            c2p[sp] = *(const f32x2*)(c2 + (size_t)b * H_SZ + col);
        }
        f32x2 bia[8];
        #pragma unroll
        for (int g = 0; g < 8; ++g)
            bia[g] = *(const f32x2*)(bias.p[g] + col);

        #pragma unroll
        for (int sp = 0; sp < 4; ++sp) {
            __syncthreads();
            // wave w writes gate w's 16 rows of this subphase (acc[sp])
            #pragma unroll
            for (int ni = 0; ni < 4; ++ni)
                #pragma unroll
                for (int j = 0; j < 4; ++j) {
                    const int rloc = hi * 4 + j;
                    glf[(w * 16 + rloc) * 64 + (((ni * 16 + fr)) ^ ((rloc & 7) << 2))] =
                        acc[sp][ni][j];
                }
            __syncthreads();

            f32x2 G[8];
            #pragma unroll
            for (int g = 0; g < 8; ++g)
                G[g] = *(const f32x2*)(glf + (g * 16 + erow) * 64 + (ecol ^ eswz));

            const int b = row0 + sp * 16 + erow;
            f32x2 hn, c1o, c2o;
            #pragma unroll
            for (int j = 0; j < 2; ++j) {
                float f1  = sigm(G[0][j] + bia[0][j]);
                float i1  = sigm(G[1][j] + bia[1][j]);
                float c1t = tanhf(G[2][j] + bia[2][j]);
                float o1  = G[3][j] + bia[3][j];
                float f2  = sigm(G[4][j] + bia[4][j]);
                float i2  = sigm(G[5][j] + bia[5][j]);
                float c2t = tanhf(G[6][j] + bia[6][j]);
                float o2  = G[7][j] + bia[7][j];
                float c1n = f1 * c1p[sp][j] + i1 * c1t;
                float c2n = f2 * c2p[sp][j] + i2 * c2t;
                float mo  = fmaxf(o1, o2);
                float e1  = __expf(o1 - mo), e2 = __expf(o2 - mo);
                float g0  = e1 / (e1 + e2);
                hn[j]  = g0 * tanhf(c1n) + (1.0f - g0) * tanhf(c2n);
                c1o[j] = c1n; c2o[j] = c2n;
            }
            const size_t o0 = (size_t)b * H_SZ + col;
            *(f32x2*)(out + o0)          = hn;
            *(f32x2*)(out + BH + o0)     = c1o;
            *(f32x2*)(out + 2 * BH + o0) = c2o;
        }
    }
}

// ---------------- host ----------------
extern "C" void kernel_launch(void* const* d_in, const int* in_sizes, int n_in,
                              void* d_out, int out_size, void* d_ws, size_t ws_size,
                              hipStream_t stream)
{
    const float* x1 = (const float*)d_in[0];
    const float* x2 = (const float*)d_in[1];
    const float* h  = (const float*)d_in[2];
    const float* c1 = (const float*)d_in[3];
    const float* c2 = (const float*)d_in[4];
    const float* wa = (const float*)d_in[21];

    // gate order: 0..3 = cell1 {f,i,c,o}; 4..7 = cell2 {f,i,c,o}
    Ptr8 wptr, bptr;
    wptr.p[0] = (const float*)d_in[5];  wptr.p[1] = (const float*)d_in[9];
    wptr.p[2] = (const float*)d_in[13]; wptr.p[3] = (const float*)d_in[17];
    wptr.p[4] = (const float*)d_in[6];  wptr.p[5] = (const float*)d_in[10];
    wptr.p[6] = (const float*)d_in[14]; wptr.p[7] = (const float*)d_in[18];
    bptr.p[0] = (const float*)d_in[7];  bptr.p[1] = (const float*)d_in[11];
    bptr.p[2] = (const float*)d_in[15]; bptr.p[3] = (const float*)d_in[19];
    bptr.p[4] = (const float*)d_in[8];  bptr.p[5] = (const float*)d_in[12];
    bptr.p[6] = (const float*)d_in[16]; bptr.p[7] = (const float*)d_in[20];

    unsigned short* Wt = (unsigned short*)d_ws;   // 1.6 MB

    pack_w<<<dim3(6, 4, 8), 256, 0, stream>>>(wptr, Wt);
    fused<<<256, 512, 0, stream>>>(x1, x2, h, c1, c2, wa, Wt, bptr, (float*)d_out);
}